// Round 1
// baseline (131.581 us; speedup 1.0000x reference)
//
#include <hip/hip_runtime.h>

#define BATCH 16
#define NN    512
#define DD    64
#define FN    32

// block: 256 threads = 4 waves; each wave handles 4 consecutive i rows.
// grid: BATCH * (NN/16) = 512 blocks.
__global__ __launch_bounds__(256) void emb_kernel(
    const float* __restrict__ prev,   // B,N,D
    const float* __restrict__ adj,    // B,N,N
    const float* __restrict__ nf,     // B,N,Fn
    const float* __restrict__ ef,     // B,N,N
    const float* __restrict__ W1,     // Fn,D
    const float* __restrict__ W2,     // D,D
    const float* __restrict__ W3,     // D,D
    const float* __restrict__ W4,     // 1,D
    float* __restrict__ out)          // B,N,D
{
    __shared__ float prevS[128 * DD];   // 32 KB chunk of prev[b]

    const int tid  = threadIdx.x;
    const int lane = tid & 63;
    const int w    = __builtin_amdgcn_readfirstlane(tid >> 6);
    const int b    = blockIdx.x >> 5;        // 32 i-groups per batch
    const int g    = blockIdx.x & 31;
    const int i0   = g * 16 + w * 4;         // first of this wave's 4 rows

    // ---- v3[lane] = sum_d relu(W4[d]) * W3[d,lane]   (once per thread)
    float v3 = 0.f;
    #pragma unroll 16
    for (int d = 0; d < DD; ++d) {
        float w4 = fmaxf(W4[d], 0.f);        // uniform load
        v3 = fmaf(w4, W3[d * DD + lane], v3);
    }

    // ---- phase 0: t[r] = sum_j adj[b,i,j] * ef[b,i,j]  (coalesced, lane-parallel)
    float t[4];
    #pragma unroll
    for (int r = 0; r < 4; ++r) {
        const int rowo = (b * NN + i0 + r) * NN;
        const float4* a4 = (const float4*)(adj + rowo);
        const float4* e4 = (const float4*)(ef + rowo);
        float tp = 0.f;
        #pragma unroll
        for (int m = 0; m < 2; ++m) {
            float4 a = a4[m * 64 + lane];
            float4 e = e4[m * 64 + lane];
            tp += a.x * e.x + a.y * e.y + a.z * e.z + a.w * e.w;
        }
        #pragma unroll
        for (int s = 1; s < 64; s <<= 1) tp += __shfl_xor(tp, s, 64);
        t[r] = tp;
    }

    // ---- phase 1: ap[lane] = sum_j adj[b,i,j] * prev[b,j,lane]
    float ap0 = 0.f, ap1 = 0.f, ap2 = 0.f, ap3 = 0.f;
    const float* a0 = adj + (b * NN + i0 + 0) * NN;
    const float* a1 = adj + (b * NN + i0 + 1) * NN;
    const float* a2 = adj + (b * NN + i0 + 2) * NN;
    const float* a3 = adj + (b * NN + i0 + 3) * NN;
    const float* pb = prev + b * NN * DD;

    for (int jc = 0; jc < NN; jc += 128) {
        // stage prev[b][jc:jc+128][:] -> LDS (contiguous 32 KB)
        const float4* src = (const float4*)(pb + jc * DD);
        float4* dst = (float4*)prevS;
        #pragma unroll
        for (int it = 0; it < 8; ++it)
            dst[it * 256 + tid] = src[it * 256 + tid];
        __syncthreads();

        #pragma unroll 8
        for (int j = 0; j < 128; ++j) {
            float aj0 = a0[jc + j];          // wave-uniform -> s_load (hoped)
            float aj1 = a1[jc + j];
            float aj2 = a2[jc + j];
            float aj3 = a3[jc + j];
            float pv  = prevS[j * DD + lane]; // 2-way bank alias = free
            ap0 = fmaf(aj0, pv, ap0);
            ap1 = fmaf(aj1, pv, ap1);
            ap2 = fmaf(aj2, pv, ap2);
            ap3 = fmaf(aj3, pv, ap3);
        }
        __syncthreads();
    }

    // ---- phase 2: epilogue per row
    float apv[4] = {ap0, ap1, ap2, ap3};
    #pragma unroll
    for (int r = 0; r < 4; ++r) {
        const int i = i0 + r;
        float x = t[r] * v3;
        // x2 = ap . W2   (broadcast ap[k] via readlane, W2 row per-lane)
        #pragma unroll
        for (int k = 0; k < DD; ++k) {
            float a = __int_as_float(
                __builtin_amdgcn_readlane(__float_as_int(apv[r]), k));
            x = fmaf(a, W2[k * DD + lane], x);
        }
        // x1 = nf . W1  (nf uniform per i)
        const float* nrow = nf + (b * NN + i) * FN;
        #pragma unroll
        for (int f = 0; f < FN; ++f)
            x = fmaf(nrow[f], W1[f * DD + lane], x);
        out[(b * NN + i) * DD + lane] = fmaxf(x, 0.f);
    }
}

extern "C" void kernel_launch(void* const* d_in, const int* in_sizes, int n_in,
                              void* d_out, int out_size, void* d_ws, size_t ws_size,
                              hipStream_t stream) {
    const float* prev = (const float*)d_in[0];
    const float* adj  = (const float*)d_in[1];
    const float* nf   = (const float*)d_in[2];
    const float* ef   = (const float*)d_in[3];
    const float* W1   = (const float*)d_in[4];
    const float* W2   = (const float*)d_in[5];
    const float* W3   = (const float*)d_in[6];
    const float* W4   = (const float*)d_in[7];
    float* out = (float*)d_out;

    emb_kernel<<<dim3(512), dim3(256), 0, stream>>>(
        prev, adj, nf, ef, W1, W2, W3, W4, out);
}

// Round 3
// 116.796 us; speedup vs baseline: 1.1266x; 1.1266x over previous
//
#include <hip/hip_runtime.h>

#define BATCH 16
#define NN    512
#define DD    64
#define FN    32
#define HALF  256     // j's per block (j-split of 2)
#define CHUNK 128     // prev rows staged per LDS pass

// ---------------- Kernel B: ap_partial = adj(half) @ prev, t_partial ----------------
// grid 512: bi -> h(2) x g(16 rowgroups) x b(16). block 256 = 4 waves, 8 rows/wave.
__global__ __launch_bounds__(256) void aggregate_kernel(
    const float* __restrict__ prev,   // B,N,D
    const float* __restrict__ adj,    // B,N,N
    const float* __restrict__ ef,     // B,N,N
    float* __restrict__ apbuf,        // [2][B*N][D]
    float* __restrict__ tbuf)         // [2][B*N]
{
    __shared__ float prevS[CHUNK * DD];   // 32 KB

    const int tid  = threadIdx.x;
    const int lane = tid & 63;
    const int w    = __builtin_amdgcn_readfirstlane(tid >> 6);
    const int bi   = blockIdx.x;
    const int h    = bi & 1;
    const int g    = (bi >> 1) & 15;
    const int b    = bi >> 5;
    const int i0   = g * 32 + w * 8;      // first of this wave's 8 rows
    const int jb   = h * HALF;

    // ---- t partial: one float4 per lane covers the 256-j half exactly
    float t[8];
    #pragma unroll
    for (int r = 0; r < 8; ++r) {
        const int rowo = (b * NN + i0 + r) * NN + jb;
        float4 a = ((const float4*)(adj + rowo))[lane];
        float4 e = ((const float4*)(ef  + rowo))[lane];
        float tp = a.x * e.x + a.y * e.y + a.z * e.z + a.w * e.w;
        #pragma unroll
        for (int s = 1; s < 64; s <<= 1) tp += __shfl_xor(tp, s, 64);
        t[r] = tp;
    }

    // ---- phase 1: acc[r][lane] = sum_j adj[i0+r][j] * prev[j][lane]
    float acc[8] = {0.f,0.f,0.f,0.f,0.f,0.f,0.f,0.f};
    const float* pb = prev + b * NN * DD + jb * DD;

    for (int c = 0; c < 2; ++c) {
        const float4* src = (const float4*)(pb + c * CHUNK * DD);
        float4* dst = (float4*)prevS;
        #pragma unroll
        for (int it = 0; it < 8; ++it)
            dst[it * 256 + tid] = src[it * 256 + tid];
        __syncthreads();

        const float* a_base = adj + (b * NN + i0) * NN + jb + c * CHUNK;
        #pragma unroll 4
        for (int j = 0; j < CHUNK; ++j) {
            float pv = prevS[j * DD + lane];     // 2-way alias = free
            #pragma unroll
            for (int r = 0; r < 8; ++r)          // wave-uniform -> s_load x4 batches
                acc[r] = fmaf(a_base[r * NN + j], pv, acc[r]);
        }
        __syncthreads();
    }

    // ---- store partials (plain stores; two disjoint slices, no atomics)
    #pragma unroll
    for (int r = 0; r < 8; ++r) {
        const int row = b * NN + i0 + r;             // [0, 8192)
        apbuf[(h * BATCH * NN + row) * DD + lane] = acc[r];
        if (lane == 0) tbuf[h * BATCH * NN + row] = t[r];
    }
}

// ---------------- Kernel C: out = relu(nf@W1 + (ap0+ap1)@W2 + (t0+t1)*v3) ----------------
// grid 512: 16 rows/block, 4 rows/wave. W2/W1 columns preloaded into VGPRs.
__global__ __launch_bounds__(256) void epilogue_kernel(
    const float* __restrict__ apbuf,
    const float* __restrict__ tbuf,
    const float* __restrict__ nf,     // B,N,Fn
    const float* __restrict__ W1,     // Fn,D
    const float* __restrict__ W2,     // D,D
    const float* __restrict__ W3,     // D,D
    const float* __restrict__ W4,     // 1,D
    float* __restrict__ out)          // B,N,D
{
    const int tid  = threadIdx.x;
    const int lane = tid & 63;
    const int w    = __builtin_amdgcn_readfirstlane(tid >> 6);
    const int row0 = blockIdx.x * 16 + w * 4;

    // preload W2 column (64 VGPR) and W1 column (32 VGPR); L2-hot
    float w2c[DD];
    #pragma unroll
    for (int k = 0; k < DD; ++k) w2c[k] = W2[k * DD + lane];
    float w1c[FN];
    #pragma unroll
    for (int f = 0; f < FN; ++f) w1c[f] = W1[f * DD + lane];

    // v3[lane] = sum_d relu(W4[d]) * W3[d,lane]
    float v3 = 0.f;
    #pragma unroll
    for (int d = 0; d < DD; ++d)
        v3 = fmaf(fmaxf(W4[d], 0.f), W3[d * DD + lane], v3);

    #pragma unroll
    for (int r = 0; r < 4; ++r) {
        const int row = row0 + r;                       // [0, 8192)
        float ap = apbuf[row * DD + lane]
                 + apbuf[(BATCH * NN + row) * DD + lane];
        float tv = tbuf[row] + tbuf[BATCH * NN + row];  // uniform
        float acc = tv * v3;
        #pragma unroll
        for (int k = 0; k < DD; ++k) {
            float a = __int_as_float(
                __builtin_amdgcn_readlane(__float_as_int(ap), k));
            acc = fmaf(a, w2c[k], acc);
        }
        const float* nrow = nf + row * FN;              // uniform loads
        #pragma unroll
        for (int f = 0; f < FN; ++f)
            acc = fmaf(nrow[f], w1c[f], acc);
        out[row * DD + lane] = fmaxf(acc, 0.f);
    }
}

extern "C" void kernel_launch(void* const* d_in, const int* in_sizes, int n_in,
                              void* d_out, int out_size, void* d_ws, size_t ws_size,
                              hipStream_t stream) {
    const float* prev = (const float*)d_in[0];
    const float* adj  = (const float*)d_in[1];
    const float* nf   = (const float*)d_in[2];
    const float* ef   = (const float*)d_in[3];
    const float* W1   = (const float*)d_in[4];
    const float* W2   = (const float*)d_in[5];
    const float* W3   = (const float*)d_in[6];
    const float* W4   = (const float*)d_in[7];
    float* out = (float*)d_out;

    float* apbuf = (float*)d_ws;                       // 2 * 8192 * 64 floats = 4 MB
    float* tbuf  = apbuf + 2 * BATCH * NN * DD;        // 2 * 8192 floats = 64 KB

    aggregate_kernel<<<dim3(512), dim3(256), 0, stream>>>(prev, adj, ef, apbuf, tbuf);
    epilogue_kernel<<<dim3(512), dim3(256), 0, stream>>>(apbuf, tbuf, nf, W1, W2, W3, W4, out);
}

// Round 5
// 102.310 us; speedup vs baseline: 1.2861x; 1.1416x over previous
//
#include <hip/hip_runtime.h>

#define NN 512
#define DD 64
#define FN 32
#define NROWS 8192            // B*N

typedef unsigned short ushortT;
typedef __attribute__((ext_vector_type(4))) unsigned short us4;
typedef __attribute__((ext_vector_type(8))) short s8;     // 8 bf16 MFMA operand
typedef __attribute__((ext_vector_type(4))) float f4;     // MFMA accumulator

__device__ inline ushortT f2bf(float x) {
    unsigned u = __float_as_uint(x);
    return (ushortT)((u + 0x7FFFu + ((u >> 16) & 1u)) >> 16);   // RNE
}

// ---------------- Kernel P: convert/transpose + t + v3 ----------------
// blocks 0..511: adj->bf16 + t   (16 rows each)
// blocks 512..527: prev -> prevT bf16 (one batch each)
// blocks 528..591: nf -> bf16
// block 592: W1T, W2T, v3
__global__ __launch_bounds__(256) void prep_kernel(
    const float* __restrict__ prev, const float* __restrict__ adj,
    const float* __restrict__ nf,   const float* __restrict__ ef,
    const float* __restrict__ W1,   const float* __restrict__ W2,
    const float* __restrict__ W3,   const float* __restrict__ W4,
    ushortT* __restrict__ adjb, ushortT* __restrict__ prevT,
    ushortT* __restrict__ nfb,  ushortT* __restrict__ W1T,
    ushortT* __restrict__ W2T,  float* __restrict__ v3,
    float* __restrict__ tbuf)
{
    const int bk = blockIdx.x, tid = threadIdx.x;

    if (bk < 512) {                       // ---- adj convert + t
        const int lane = tid & 63, w = tid >> 6;
        const int row0 = bk * 16 + w * 4;
        #pragma unroll
        for (int r = 0; r < 4; ++r) {
            const int row = row0 + r;
            const float4* a4 = (const float4*)(adj + row * NN);
            const float4* e4 = (const float4*)(ef  + row * NN);
            float4 a0 = a4[lane], a1 = a4[64 + lane];
            float4 e0 = e4[lane], e1 = e4[64 + lane];
            float tp = a0.x*e0.x + a0.y*e0.y + a0.z*e0.z + a0.w*e0.w
                     + a1.x*e1.x + a1.y*e1.y + a1.z*e1.z + a1.w*e1.w;
            #pragma unroll
            for (int s = 1; s < 64; s <<= 1) tp += __shfl_xor(tp, s, 64);
            us4 o0 = { f2bf(a0.x), f2bf(a0.y), f2bf(a0.z), f2bf(a0.w) };
            us4 o1 = { f2bf(a1.x), f2bf(a1.y), f2bf(a1.z), f2bf(a1.w) };
            ((us4*)(adjb + row * NN))[lane]      = o0;
            ((us4*)(adjb + row * NN))[64 + lane] = o1;
            if (lane == 0) tbuf[row] = tp;
        }
    } else if (bk < 528) {                // ---- prev transpose (batch b)
        __shared__ float T[64][65];
        const int b = bk - 512;
        for (int c = 0; c < 8; ++c) {     // 64-row chunk of j
            #pragma unroll
            for (int s = 0; s < 16; ++s) {
                int idx = s * 256 + tid;
                int jl = idx >> 6, d = idx & 63;
                T[jl][d] = prev[b * NN * DD + (c * 64 + jl) * DD + d];
            }
            __syncthreads();
            #pragma unroll
            for (int s = 0; s < 16; ++s) {
                int idx = s * 256 + tid;
                int d = idx >> 6, jl = idx & 63;
                prevT[b * DD * NN + d * NN + c * 64 + jl] = f2bf(T[jl][d]);
            }
            __syncthreads();
        }
    } else if (bk < 592) {                // ---- nf convert (coalesced float4)
        const int base = (bk - 528) * 4096;
        #pragma unroll
        for (int s = 0; s < 4; ++s) {
            int i = base + s * 1024 + tid * 4;
            float4 v = *(const float4*)(nf + i);
            us4 o = { f2bf(v.x), f2bf(v.y), f2bf(v.z), f2bf(v.w) };
            *(us4*)(nfb + i) = o;
        }
    } else {                              // ---- weights
        for (int i = tid; i < DD * FN; i += 256) {      // W1T[e][f]
            int e = i >> 5, f = i & 31;
            W1T[i] = f2bf(W1[f * DD + e]);
        }
        for (int i = tid; i < DD * DD; i += 256) {      // W2T[e][d]
            int e = i >> 6, d = i & 63;
            W2T[i] = f2bf(W2[d * DD + e]);
        }
        if (tid < DD) {
            float s = 0.f;
            for (int d = 0; d < DD; ++d)
                s = fmaf(fmaxf(W4[d], 0.f), W3[d * DD + tid], s);
            v3[tid] = s;
        }
    }
}

// ---------------- Kernel G: one wave per 16-row tile, MFMA everything ----------------
// out = relu( t*v3  +  nf@W1  +  (adj@prev)@W2 )
__global__ __launch_bounds__(64) void gemm_kernel(
    const ushortT* __restrict__ adjb, const ushortT* __restrict__ prevT,
    const ushortT* __restrict__ nfb,  const ushortT* __restrict__ W1T,
    const ushortT* __restrict__ W2T,  const float* __restrict__ v3,
    const float* __restrict__ tbuf,   float* __restrict__ out)
{
    __shared__ __align__(16) ushortT PT[16 * 72];   // ap tile, pitch 72 (16B-aligned rows)

    const int l   = threadIdx.x;          // 0..63
    const int i0  = blockIdx.x * 16;      // global row base
    const int b   = i0 >> 9;              // batch
    const int l15 = l & 15, g = l >> 4;

    // ---- ap = adj @ prev  (K=512, 16 k-steps, 4 n-tiles)
    f4 zero = {0.f, 0.f, 0.f, 0.f};
    f4 acc[4] = {zero, zero, zero, zero};
    const ushortT* arow = adjb  + (i0 + l15) * NN + 8 * g;
    const ushortT* pb   = prevT + b * DD * NN + l15 * NN + 8 * g;

    #pragma unroll
    for (int ks = 0; ks < 16; ++ks) {
        s8 A = *(const s8*)(arow + 32 * ks);
        #pragma unroll
        for (int nt = 0; nt < 4; ++nt) {
            s8 B = *(const s8*)(pb + nt * 16 * NN + 32 * ks);
            acc[nt] = __builtin_amdgcn_mfma_f32_16x16x32_bf16(A, B, acc[nt], 0, 0, 0);
        }
    }

    // ---- transpose ap (C-layout -> A-layout) via per-wave LDS, as bf16
    #pragma unroll
    for (int nt = 0; nt < 4; ++nt)
        #pragma unroll
        for (int r = 0; r < 4; ++r)
            PT[(4 * g + r) * 72 + 16 * nt + l15] = f2bf(acc[nt][r]);

    // ---- o init = t[row] * v3[col]   (rank-1 term)
    float tr[4];
    #pragma unroll
    for (int r = 0; r < 4; ++r) tr[r] = tbuf[i0 + 4 * g + r];
    f4 o[4];
    #pragma unroll
    for (int nt = 0; nt < 4; ++nt) {
        float vv = v3[16 * nt + l15];
        o[nt][0] = tr[0] * vv; o[nt][1] = tr[1] * vv;
        o[nt][2] = tr[2] * vv; o[nt][3] = tr[3] * vv;
    }

    // ---- x1 = nf @ W1   (K=32, single k-step)
    s8 A1 = *(const s8*)(nfb + (i0 + l15) * FN + 8 * g);
    #pragma unroll
    for (int nt = 0; nt < 4; ++nt) {
        s8 B1 = *(const s8*)(W1T + (16 * nt + l15) * FN + 8 * g);
        o[nt] = __builtin_amdgcn_mfma_f32_16x16x32_bf16(A1, B1, o[nt], 0, 0, 0);
    }

    // ---- x2 = ap @ W2   (K=64, 2 k-steps; A2 fragments from LDS)
    #pragma unroll
    for (int k2 = 0; k2 < 2; ++k2) {
        s8 A2 = *(const s8*)(&PT[l15 * 72 + 32 * k2 + 8 * g]);
        #pragma unroll
        for (int nt = 0; nt < 4; ++nt) {
            s8 B2 = *(const s8*)(W2T + (16 * nt + l15) * DD + 32 * k2 + 8 * g);
            o[nt] = __builtin_amdgcn_mfma_f32_16x16x32_bf16(A2, B2, o[nt], 0, 0, 0);
        }
    }

    // ---- relu + store (fp32)
    float* orow = out + i0 * DD;
    #pragma unroll
    for (int nt = 0; nt < 4; ++nt)
        #pragma unroll
        for (int r = 0; r < 4; ++r)
            orow[(4 * g + r) * DD + 16 * nt + l15] = fmaxf(o[nt][r], 0.f);
}

extern "C" void kernel_launch(void* const* d_in, const int* in_sizes, int n_in,
                              void* d_out, int out_size, void* d_ws, size_t ws_size,
                              hipStream_t stream) {
    const float* prev = (const float*)d_in[0];
    const float* adj  = (const float*)d_in[1];
    const float* nf   = (const float*)d_in[2];
    const float* ef   = (const float*)d_in[3];
    const float* W1   = (const float*)d_in[4];
    const float* W2   = (const float*)d_in[5];
    const float* W3   = (const float*)d_in[6];
    const float* W4   = (const float*)d_in[7];
    float* out = (float*)d_out;

    char* ws = (char*)d_ws;                                // byte offsets, all 16B-aligned
    ushortT* adjb  = (ushortT*)(ws + 0);                   //  8,388,608 B
    ushortT* prevT = (ushortT*)(ws + 8388608);             //  1,048,576 B
    ushortT* nfb   = (ushortT*)(ws + 9437184);             //    524,288 B
    ushortT* W1T   = (ushortT*)(ws + 9961472);             //      4,096 B
    ushortT* W2T   = (ushortT*)(ws + 9965568);             //      8,192 B
    float*   v3    = (float*)  (ws + 9973760);             //        256 B
    float*   tbuf  = (float*)  (ws + 9974016);             //     32,768 B

    prep_kernel<<<dim3(593), dim3(256), 0, stream>>>(
        prev, adj, nf, ef, W1, W2, W3, W4, adjb, prevT, nfb, W1T, W2T, v3, tbuf);
    gemm_kernel<<<dim3(512), dim3(64), 0, stream>>>(
        adjb, prevT, nfb, W1T, W2T, v3, tbuf, out);
}

// Round 7
// 101.883 us; speedup vs baseline: 1.2915x; 1.0042x over previous
//
#include <hip/hip_runtime.h>

#define NN 512
#define DD 64
#define FN 32

typedef unsigned short ushortT;
typedef __attribute__((ext_vector_type(4))) unsigned short us4;
typedef __attribute__((ext_vector_type(8))) short s8;     // 8 bf16 MFMA operand
typedef __attribute__((ext_vector_type(4))) float f4;     // MFMA accumulator

__device__ inline ushortT f2bf(float x) {
    unsigned u = __float_as_uint(x);
    return (ushortT)((u + 0x7FFFu + ((u >> 16) & 1u)) >> 16);   // RNE
}

// ---------------- Kernel P (small): prevT + nf bf16 + weights ----------------
// blocks 0..15: prev -> prevT bf16 (one batch each)
// blocks 16..79: nf -> bf16
// block 80: W1T, W2T, v3
__global__ __launch_bounds__(256) void prep_kernel(
    const float* __restrict__ prev, const float* __restrict__ nf,
    const float* __restrict__ W1,   const float* __restrict__ W2,
    const float* __restrict__ W3,   const float* __restrict__ W4,
    ushortT* __restrict__ prevT, ushortT* __restrict__ nfb,
    ushortT* __restrict__ W1T,   ushortT* __restrict__ W2T,
    float* __restrict__ v3)
{
    const int bk = blockIdx.x, tid = threadIdx.x;

    if (bk < 16) {                        // ---- prev transpose (batch b)
        __shared__ float T[64][65];
        const int b = bk;
        for (int c = 0; c < 8; ++c) {     // 64-row chunk of j
            #pragma unroll
            for (int s = 0; s < 16; ++s) {
                int idx = s * 256 + tid;
                int jl = idx >> 6, d = idx & 63;
                T[jl][d] = prev[b * NN * DD + (c * 64 + jl) * DD + d];
            }
            __syncthreads();
            #pragma unroll
            for (int s = 0; s < 16; ++s) {
                int idx = s * 256 + tid;
                int d = idx >> 6, jl = idx & 63;
                prevT[b * DD * NN + d * NN + c * 64 + jl] = f2bf(T[jl][d]);
            }
            __syncthreads();
        }
    } else if (bk < 80) {                 // ---- nf convert (coalesced float4)
        const int base = (bk - 16) * 4096;
        #pragma unroll
        for (int s = 0; s < 4; ++s) {
            int i = base + s * 1024 + tid * 4;
            float4 v = *(const float4*)(nf + i);
            us4 o = { f2bf(v.x), f2bf(v.y), f2bf(v.z), f2bf(v.w) };
            *(us4*)(nfb + i) = o;
        }
    } else {                              // ---- weights
        for (int i = tid; i < DD * FN; i += 256) {      // W1T[e][f]
            int e = i >> 5, f = i & 31;
            W1T[i] = f2bf(W1[f * DD + e]);
        }
        for (int i = tid; i < DD * DD; i += 256) {      // W2T[e][d]
            int e = i >> 6, d = i & 63;
            W2T[i] = f2bf(W2[d * DD + e]);
        }
        if (tid < DD) {
            float s = 0.f;
            for (int d = 0; d < DD; ++d)
                s = fmaf(fmaxf(W4[d], 0.f), W3[d * DD + tid], s);
            v3[tid] = s;
        }
    }
}

// ---------------- Kernel G: fused adj/ef load + t + MFMA, K split 4 ways ----------------
// block = 256 thr = 4 waves, 16 output rows. wave w owns K-slice [128w,128w+128)
// then C-reduce in LDS; epilogue: wave w owns output col-tile nt = w.
#define APITCH 136            // bf16 elems per adjS row (272 B: 2-way bank alias)
#define CPITCH 68             // f32 per Cpart row (272 B)
__global__ __launch_bounds__(256) void gemm_kernel(
    const float* __restrict__ adj,   const float* __restrict__ ef,
    const ushortT* __restrict__ prevT, const ushortT* __restrict__ nfb,
    const ushortT* __restrict__ W1T, const ushortT* __restrict__ W2T,
    const float* __restrict__ v3,    float* __restrict__ out)
{
    __shared__ __align__(16) ushortT adjS[4 * 16 * APITCH];  // 17408 B
    __shared__ __align__(16) float   Cpart[4 * 16 * CPITCH]; // 17408 B
    __shared__ __align__(16) ushortT PT[16 * 72];            //  2304 B
    __shared__ float tpart[4][16];
    __shared__ float tsum[16];

    const int tid  = threadIdx.x;
    const int lane = tid & 63;
    const int w    = __builtin_amdgcn_readfirstlane(tid >> 6);
    const int i0   = blockIdx.x * 16;
    const int b    = blockIdx.x >> 5;
    const int l15  = lane & 15, g = lane >> 4;
    const int l31  = lane & 31, half = lane >> 5;

    // ---- phase A: load adj/ef fp32 (own K-slice), t-partial, convert -> LDS
    #pragma unroll
    for (int it = 0; it < 8; ++it) {
        const int r = 2 * it + half;
        const float4* a4 = (const float4*)(adj + (i0 + r) * NN + 128 * w);
        const float4* e4 = (const float4*)(ef  + (i0 + r) * NN + 128 * w);
        float4 av = a4[l31], ev = e4[l31];
        float tp = av.x*ev.x + av.y*ev.y + av.z*ev.z + av.w*ev.w;
        #pragma unroll
        for (int s = 1; s < 32; s <<= 1) tp += __shfl_xor(tp, s, 64);
        if (l31 == 0) tpart[w][r] = tp;
        us4 ov = { f2bf(av.x), f2bf(av.y), f2bf(av.z), f2bf(av.w) };
        *(us4*)(&adjS[w * 16 * APITCH + r * APITCH + 4 * l31]) = ov;
    }

    // ---- phase B: ap partial = adj_slice @ prev_slice (4 k-steps)
    f4 zero = {0.f, 0.f, 0.f, 0.f};
    f4 acc[4] = {zero, zero, zero, zero};
    const ushortT* pb = prevT + b * DD * NN + l15 * NN + 128 * w + 8 * g;
    #pragma unroll
    for (int ksl = 0; ksl < 4; ++ksl) {
        s8 A = *(const s8*)(&adjS[w * 16 * APITCH + l15 * APITCH + 32 * ksl + 8 * g]);
        #pragma unroll
        for (int nt = 0; nt < 4; ++nt) {
            s8 B = *(const s8*)(pb + nt * 16 * NN + 32 * ksl);
            acc[nt] = __builtin_amdgcn_mfma_f32_16x16x32_bf16(A, B, acc[nt], 0, 0, 0);
        }
    }

    // ---- write C partials
    #pragma unroll
    for (int nt = 0; nt < 4; ++nt)
        #pragma unroll
        for (int r = 0; r < 4; ++r)
            Cpart[w * 16 * CPITCH + (4 * g + r) * CPITCH + 16 * nt + l15] = acc[nt][r];
    __syncthreads();

    // ---- reduce C across waves -> PT (bf16, A-layout for ap@W2); reduce t
    {
        const int row = tid >> 4, c0 = (tid & 15) * 4;
        us4 o;
        #pragma unroll
        for (int c = 0; c < 4; ++c) {
            float s = Cpart[0 * 16 * CPITCH + row * CPITCH + c0 + c]
                    + Cpart[1 * 16 * CPITCH + row * CPITCH + c0 + c]
                    + Cpart[2 * 16 * CPITCH + row * CPITCH + c0 + c]
                    + Cpart[3 * 16 * CPITCH + row * CPITCH + c0 + c];
            o[c] = f2bf(s);
        }
        *(us4*)(&PT[row * 72 + c0]) = o;
        if (tid < 16)
            tsum[tid] = tpart[0][tid] + tpart[1][tid] + tpart[2][tid] + tpart[3][tid];
    }
    __syncthreads();

    // ---- epilogue: wave w owns col-tile nt = w
    float vv = v3[16 * w + l15];
    f4 o;
    #pragma unroll
    for (int r = 0; r < 4; ++r) o[r] = tsum[4 * g + r] * vv;

    s8 A1 = *(const s8*)(nfb + (i0 + l15) * FN + 8 * g);
    s8 B1 = *(const s8*)(W1T + (16 * w + l15) * FN + 8 * g);
    o = __builtin_amdgcn_mfma_f32_16x16x32_bf16(A1, B1, o, 0, 0, 0);

    #pragma unroll
    for (int k2 = 0; k2 < 2; ++k2) {
        s8 A2 = *(const s8*)(&PT[l15 * 72 + 32 * k2 + 8 * g]);
        s8 B2 = *(const s8*)(W2T + (16 * w + l15) * DD + 32 * k2 + 8 * g);
        o = __builtin_amdgcn_mfma_f32_16x16x32_bf16(A2, B2, o, 0, 0, 0);
    }

    float* orow = out + i0 * DD;
    #pragma unroll
    for (int r = 0; r < 4; ++r)
        orow[(4 * g + r) * DD + 16 * w + l15] = fmaxf(o[r], 0.f);
}

extern "C" void kernel_launch(void* const* d_in, const int* in_sizes, int n_in,
                              void* d_out, int out_size, void* d_ws, size_t ws_size,
                              hipStream_t stream) {
    const float* prev = (const float*)d_in[0];
    const float* adj  = (const float*)d_in[1];
    const float* nf   = (const float*)d_in[2];
    const float* ef   = (const float*)d_in[3];
    const float* W1   = (const float*)d_in[4];
    const float* W2   = (const float*)d_in[5];
    const float* W3   = (const float*)d_in[6];
    const float* W4   = (const float*)d_in[7];
    float* out = (float*)d_out;

    char* ws = (char*)d_ws;                                // byte offsets, 16B-aligned
    ushortT* prevT = (ushortT*)(ws + 0);                   // 1,048,576 B
    ushortT* nfb   = (ushortT*)(ws + 1048576);             //   524,288 B
    ushortT* W1T   = (ushortT*)(ws + 1572864);             //     4,096 B
    ushortT* W2T   = (ushortT*)(ws + 1576960);             //     8,192 B
    float*   v3    = (float*)  (ws + 1585152);             //       256 B

    prep_kernel<<<dim3(81), dim3(256), 0, stream>>>(
        prev, nf, W1, W2, W3, W4, prevT, nfb, W1T, W2T, v3);
    gemm_kernel<<<dim3(512), dim3(256), 0, stream>>>(
        adj, ef, prevT, nfb, W1T, W2T, v3, out);
}